// Round 23
// baseline (214.842 us; speedup 1.0000x reference)
//
#include <hip/hip_runtime.h>

typedef _Float16 half_t;
typedef __attribute__((ext_vector_type(8))) _Float16 f16x8;   // 8 fp16 = 4 VGPRs
typedef __attribute__((ext_vector_type(4))) _Float16 f16x4;
typedef __attribute__((ext_vector_type(4))) float f32x4;
typedef __attribute__((ext_vector_type(4))) float float4v;

__device__ __forceinline__ void gload_lds16(const void* g, void* l) {
  __builtin_amdgcn_global_load_lds(
      (const __attribute__((address_space(1))) void*)g,
      (__attribute__((address_space(3))) void*)l, 16, 0, 0);
}

// ---------------------------------------------------------------------------
// Big-GEMM (8-phase): C[16384][1024] = A * B, Bt = B^T [1024][1024].
// OUTMODE 0: f32 standard ; OUTMODE 2: f16 head-blocked [b][h][l][d]
// AMODE 0: A row-major ; AMODE 1: A head-blocked [b][h][l][64]
// T1: XCD-aware bijective block swizzle (grid 64x4 = 256 = 8*32): each XCD
// gets 32 consecutive m-tiles in one n-band -> B-panel L2-resident.
// ---------------------------------------------------------------------------
template<int OUTMODE, int AMODE>
__global__ __launch_bounds__(512, 2)
void gemm_big(const half_t* __restrict__ A, const half_t* __restrict__ Bt,
              void* __restrict__ Cv, const float* __restrict__ bias, float alpha)
{
  __shared__ __attribute__((aligned(16))) char lds[131072];
  const int tid = threadIdx.x, w = tid >> 6, lane = tid & 63;
  const int wr = w >> 2, wc = w & 3;          // wave grid 2M x 4N
  const int g = lane >> 4, cc = lane & 15;
  // T1 XCD swizzle: wg in [0,256), swz = (wg%8)*32 + wg/8 (bijective)
  const int wg = blockIdx.x + (blockIdx.y << 6);
  const int swz = ((wg & 7) << 5) + (wg >> 3);
  const int m0 = (swz & 63) * 256, n0 = (swz >> 6) * 256;

  const int srow2 = tid >> 2, sslot = tid & 3;
  const int swslot = sslot ^ ((srow2 >> 1) & 3);     // inverse swizzle on source
  const int swr = (g ^ ((cc >> 1) & 3)) << 4;        // swizzled read slot

  const f32x4 zero = {0.f, 0.f, 0.f, 0.f};
  f32x4 acc[8][4];
#pragma unroll
  for (int i = 0; i < 8; ++i)
#pragma unroll
    for (int j = 0; j < 4; ++j) acc[i][j] = zero;

  auto STAGE_HALF = [&](int ktile, int hh, char* sb) {
    const int kk = hh >> 1, isB = hh & 1;
    char* d = sb + isB * 32768 + kk * 16384;
    if (!isB && AMODE == 1) {
      const int r0 = m0 + srow2, r1 = r0 + 128;
      const long a0 = (((long)((r0 >> 12) * 16 + ktile) * 4096 + (r0 & 4095)) << 6)
                      + kk * 32 + swslot * 8;
      const long a1 = (((long)((r1 >> 12) * 16 + ktile) * 4096 + (r1 & 4095)) << 6)
                      + kk * 32 + swslot * 8;
      gload_lds16(A + a0, d + tid * 16);
      gload_lds16(A + a1, d + 8192 + tid * 16);
    } else {
      const half_t* src = isB ? Bt : A;
      const int base_row = isB ? n0 : m0;
      const long rowoff = (long)(base_row + srow2) * 1024 + ktile * 64 + kk * 32 + swslot * 8;
      gload_lds16(src + rowoff,          d + tid * 16);
      gload_lds16(src + rowoff + 131072, d + 8192 + tid * 16);
    }
  };

  {
    char* b0 = lds;
    STAGE_HALF(0, 0, b0); STAGE_HALF(0, 1, b0);
    STAGE_HALF(0, 2, b0); STAGE_HALF(0, 3, b0);
  }
  asm volatile("s_waitcnt vmcnt(4)" ::: "memory");
  __builtin_amdgcn_s_barrier();

#pragma unroll 1
  for (int n = 0; n < 16; ++n) {
    const char* rb = lds + ((n & 1) << 16);
    char* sb = lds + (((n + 1) & 1) << 16);
    f16x8 bf[4];
#pragma unroll
    for (int ph = 0; ph < 4; ++ph) {
      const int kk = ph >> 1, fh = ph & 1;
      f16x8 af[4];
      const char* Ah = rb + kk * 16384;
#pragma unroll
      for (int mf = 0; mf < 4; ++mf)
        af[mf] = *(const f16x8*)(Ah + (wr * 128 + fh * 64 + mf * 16 + cc) * 64 + swr);
      if (fh == 0) {
        const char* Bh = rb + 32768 + kk * 16384;
#pragma unroll
        for (int nf = 0; nf < 4; ++nf)
          bf[nf] = *(const f16x8*)(Bh + (wc * 64 + nf * 16 + cc) * 64 + swr);
      }
      if (n < 15) STAGE_HALF(n + 1, ph, sb);
      __builtin_amdgcn_sched_barrier(0);
      __builtin_amdgcn_s_barrier();
      asm volatile("s_waitcnt lgkmcnt(0)" ::: "memory");
      __builtin_amdgcn_sched_barrier(0);
      __builtin_amdgcn_s_setprio(1);
#pragma unroll
      for (int mf = 0; mf < 4; ++mf)
#pragma unroll
        for (int nf = 0; nf < 4; ++nf)
          acc[fh * 4 + mf][nf] =
              __builtin_amdgcn_mfma_f32_16x16x32_f16(af[mf], bf[nf], acc[fh * 4 + mf][nf], 0, 0, 0);
      __builtin_amdgcn_s_setprio(0);
      __builtin_amdgcn_sched_barrier(0);
      if (ph == 1) {
        if (n < 15) { asm volatile("s_waitcnt vmcnt(4)" ::: "memory"); }
        else        { asm volatile("s_waitcnt vmcnt(0)" ::: "memory"); }
      } else if (ph == 3) {
        if (n < 15) { asm volatile("s_waitcnt vmcnt(4)" ::: "memory"); }
      }
      __builtin_amdgcn_s_barrier();
    }
  }

#pragma unroll
  for (int mf = 0; mf < 8; ++mf)
#pragma unroll
    for (int nf = 0; nf < 4; ++nf)
#pragma unroll
      for (int r = 0; r < 4; ++r) {
        const int row = m0 + wr * 128 + mf * 16 + g * 4 + r;  // D: row=(l>>4)*4+reg
        const int col = n0 + wc * 64 + nf * 16 + cc;          //    col=l&15
        float v = (acc[mf][nf][r] + bias[col]) * alpha;
        if (OUTMODE == 0) {
          ((float*)Cv)[(long)row * 1024 + col] = v;
        } else {
          const int bb = row >> 12, l = row & 4095, h = col >> 6, d = col & 63;
          ((half_t*)Cv)[(((long)(bb * 16 + h) * 4096 + l) << 6) + d] = (half_t)v;
        }
      }
}

// ---------------------------------------------------------------------------
// Split-K GEMM for xEF: partials, plain f32 stores to slice ks.
// ---------------------------------------------------------------------------
template<int SK>
__global__ __launch_bounds__(256, 2)
void gemm_xef(const half_t* __restrict__ A, const half_t* __restrict__ Bt,
              float* __restrict__ Cv, int lda, int ldb, long sB, long sC)
{
  __shared__ __attribute__((aligned(16))) half_t As[128 * 32];
  __shared__ __attribute__((aligned(16))) half_t Bs[128 * 32];

  const int tid = threadIdx.x, w = tid >> 6, lane = tid & 63;
  const int wr = w >> 1, wc = w & 1;
  const int z = blockIdx.z / SK, ks = blockIdx.z % SK;
  const half_t* Ab = A;
  const half_t* Bb = Bt + (long)z * sB;
  const int m0 = blockIdx.x * 128, n0 = blockIdx.y * 128;
  const int g = lane >> 4, cc = lane & 15;
  const int srow = lane >> 2, scol = (lane & 3) * 8;

  const f32x4 zero = {0.f, 0.f, 0.f, 0.f};
  f32x4 acc[4][4];
#pragma unroll
  for (int i = 0; i < 4; ++i)
#pragma unroll
    for (int j = 0; j < 4; ++j) acc[i][j] = zero;

  const int kchunk = 4096 / SK;
  for (int kt = ks * kchunk; kt < (ks + 1) * kchunk; kt += 32) {
#pragma unroll
    for (int j = 0; j < 2; ++j) {
      const int bi = w * 2 + j;
      gload_lds16(Ab + (long)(m0 + bi * 16 + srow) * lda + kt + scol, &As[bi * 512]);
      gload_lds16(Bb + (long)(n0 + bi * 16 + srow) * ldb + kt + scol, &Bs[bi * 512]);
    }
    __syncthreads();

    f16x8 af[4], bf[4];
#pragma unroll
    for (int i = 0; i < 4; ++i)
      af[i] = *(const f16x8*)&As[(wr * 64 + i * 16 + cc) * 32 + g * 8];
#pragma unroll
    for (int j = 0; j < 4; ++j)
      bf[j] = *(const f16x8*)&Bs[(wc * 64 + j * 16 + cc) * 32 + g * 8];
#pragma unroll
    for (int i = 0; i < 4; ++i)
#pragma unroll
      for (int j = 0; j < 4; ++j)
        acc[i][j] = __builtin_amdgcn_mfma_f32_16x16x32_f16(af[i], bf[j], acc[i][j], 0, 0, 0);
    __syncthreads();
  }

  const int nb = gridDim.z / SK;
#pragma unroll
  for (int i = 0; i < 4; ++i)
#pragma unroll
    for (int j = 0; j < 4; ++j)
#pragma unroll
      for (int r = 0; r < 4; ++r) {
        const int row = m0 + wr * 64 + i * 16 + g * 4 + r;
        const int col = n0 + wc * 64 + j * 16 + cc;
        Cv[((long)ks * nb + z) * sC + (long)row * 1024 + col] = acc[i][j][r];
      }
}

// ---------------------------------------------------------------------------
// Merged kE + vF GEMM (64x64 tiles, K=1024, 512 blocks).
// ---------------------------------------------------------------------------
__global__ __launch_bounds__(256, 2)
void gemm_kevf(const half_t* __restrict__ xEF, const half_t* __restrict__ Wkt,
               const half_t* __restrict__ Wvt, half_t* __restrict__ kEb,
               half_t* __restrict__ vFtb, const float* __restrict__ bk,
               const float* __restrict__ bv, const float* __restrict__ sEF)
{
  __shared__ __attribute__((aligned(16))) half_t As[64 * 32];
  __shared__ __attribute__((aligned(16))) half_t Bs[64 * 32];
  const int tid = threadIdx.x, w = tid >> 6, lane = tid & 63;
  const int wr = w >> 1, wc = w & 1;
  const int g = lane >> 4, cc = lane & 15;
  const int srow = lane >> 2, scol = (lane & 3) * 8;

  const int bid = blockIdx.x;
  const int role = bid >> 8, lb = bid & 255;
  const half_t *Ap, *Bp;
  int m0, n0, z;
  if (role == 0) {
    m0 = (lb & 3) * 64; n0 = ((lb >> 2) & 15) * 64; z = lb >> 6;
    Ap = xEF + (long)z * 524288;  Bp = Wkt;
  } else {
    m0 = (lb & 15) * 64; n0 = ((lb >> 4) & 3) * 64; z = lb >> 6;
    Ap = Wvt;  Bp = xEF + (long)z * 524288 + 262144;
  }

  const f32x4 zero = {0.f, 0.f, 0.f, 0.f};
  f32x4 acc[2][2];
#pragma unroll
  for (int i = 0; i < 2; ++i)
#pragma unroll
    for (int j = 0; j < 2; ++j) acc[i][j] = zero;

  for (int kt = 0; kt < 1024; kt += 32) {
    gload_lds16(Ap + (long)(m0 + w * 16 + srow) * 1024 + kt + scol, &As[w * 512]);
    gload_lds16(Bp + (long)(n0 + w * 16 + srow) * 1024 + kt + scol, &Bs[w * 512]);
    __syncthreads();
    f16x8 af[2], bf[2];
#pragma unroll
    for (int i = 0; i < 2; ++i)
      af[i] = *(const f16x8*)&As[(wr * 32 + i * 16 + cc) * 32 + g * 8];
#pragma unroll
    for (int j = 0; j < 2; ++j)
      bf[j] = *(const f16x8*)&Bs[(wc * 32 + j * 16 + cc) * 32 + g * 8];
#pragma unroll
    for (int i = 0; i < 2; ++i)
#pragma unroll
      for (int j = 0; j < 2; ++j)
        acc[i][j] = __builtin_amdgcn_mfma_f32_16x16x32_f16(af[i], bf[j], acc[i][j], 0, 0, 0);
    __syncthreads();
  }

#pragma unroll
  for (int i = 0; i < 2; ++i)
#pragma unroll
    for (int j = 0; j < 2; ++j)
#pragma unroll
      for (int r = 0; r < 4; ++r) {
        const int row = m0 + wr * 32 + i * 16 + g * 4 + r;
        const int col = n0 + wc * 32 + j * 16 + cc;
        float v = acc[i][j][r];
        if (role == 0) {
          v += sEF[row] * bk[col];
          kEb[(long)z * 262144 + (long)(col >> 6) * 16384 + (long)row * 64 + (col & 63)]
              = (half_t)v;
        } else {
          v += bv[row] * sEF[256 + col];
          vFtb[(long)z * 262144 + (long)row * 256 + col] = (half_t)v;
        }
      }
}

// ---------------------------------------------------------------------------
// Fused attention v9b (single-tile): stage kE+vF per block, one 256-row
// q-tile per block (grid 16x16x4). exp2 softmax (logits pre-scaled by log2e),
// T13 defer-max. Output head-blocked [b][h][l][d].
// ---------------------------------------------------------------------------
__global__ __launch_bounds__(512, 2)
void attn_fused(const half_t* __restrict__ qhb, const half_t* __restrict__ kEh,
                const half_t* __restrict__ vFt, half_t* __restrict__ outp, int L)
{
  __shared__ __attribute__((aligned(16))) half_t Ks[256 * 64];  // 32KB
  __shared__ __attribute__((aligned(16))) half_t Vs[64 * 256];  // 32KB
  const int tid = threadIdx.x, w = tid >> 6, lane = tid & 63;
  const int g = lane >> 4, c = lane & 15;
  const int l0 = blockIdx.x * 256, h = blockIdx.y, b = blockIdx.z;

  const half_t* keh = kEh + (long)(b * 16 + h) * 16384;          // [256][64]
  const half_t* vfh = vFt + (long)b * 262144 + (long)h * 16384;  // [64][256]

  // ---- stage kE -> Ks and vF -> Vs (swizzled source, linear dest) ----
#pragma unroll
  for (int i = 0; i < 4; ++i) {
    const int row = i * 64 + (tid >> 3), slot = tid & 7;
    gload_lds16(keh + row * 64 + ((slot ^ (row & 7)) << 3),
                (char*)Ks + i * 8192 + tid * 16);
  }
#pragma unroll
  for (int i = 0; i < 4; ++i) {
    const int row = i * 16 + (tid >> 5), slot = tid & 31;
    gload_lds16(vfh + row * 256 + ((slot ^ (row & 7)) << 3),
                (char*)Vs + i * 8192 + tid * 16);
  }

  const long lbase = (long)(b * 16 + h) * 4096 + l0;
  const half_t* qpan = qhb + lbase * 64;          // [256][64]
  half_t* ob = outp + (lbase + w * 32) * 64;      // head-blocked out

  // q direct to registers (overlaps the staging loads)
  f16x8 qf[2][2];
#pragma unroll
  for (int fi = 0; fi < 2; ++fi)
#pragma unroll
    for (int ks = 0; ks < 2; ++ks)
      qf[fi][ks] = *(const f16x8*)(qpan + (w * 32 + fi * 16 + c) * 64 + ks * 32 + g * 8);

  __syncthreads();   // staged kE/vF visible

  const f32x4 zero = {0.f, 0.f, 0.f, 0.f};
  f32x4 o[2][4];
#pragma unroll
  for (int fi = 0; fi < 2; ++fi)
#pragma unroll
    for (int fd = 0; fd < 4; ++fd) o[fi][fd] = zero;
  float mrun[2] = {-3.0e38f, -3.0e38f};
  float lrun[2] = {0.f, 0.f};

  for (int ch = 0; ch < 4; ++ch) {
    // --- QK^T chunk from LDS: S^T = kE · q^T ---
    f32x4 s[2][4];
#pragma unroll
    for (int fi = 0; fi < 2; ++fi)
#pragma unroll
      for (int fj = 0; fj < 4; ++fj) s[fi][fj] = zero;
#pragma unroll
    for (int fj = 0; fj < 4; ++fj) {
      const int krow = ch * 64 + fj * 16 + c;
      const char* kb = (const char*)Ks + krow * 128;
      f16x8 k0 = *(const f16x8*)(kb + ((g ^ (c & 7)) << 4));
      f16x8 k1 = *(const f16x8*)(kb + (((4 + g) ^ (c & 7)) << 4));
#pragma unroll
      for (int fi = 0; fi < 2; ++fi) {
        s[fi][fj] = __builtin_amdgcn_mfma_f32_16x16x32_f16(k0, qf[fi][0], s[fi][fj], 0, 0, 0);
        s[fi][fj] = __builtin_amdgcn_mfma_f32_16x16x32_f16(k1, qf[fi][1], s[fi][fj], 0, 0, 0);
      }
    }

    // --- online softmax (log2-domain, native exp2) with defer-max ---
    f16x4 p[2][4];
#pragma unroll
    for (int fi = 0; fi < 2; ++fi) {
      float cm = -3.0e38f;
#pragma unroll
      for (int fj = 0; fj < 4; ++fj)
#pragma unroll
        for (int r = 0; r < 4; ++r) cm = fmaxf(cm, s[fi][fj][r]);
      cm = fmaxf(cm, __shfl_xor(cm, 16));
      cm = fmaxf(cm, __shfl_xor(cm, 32));
      const float mref = mrun[fi];
      const bool keep = __all(cm - mref <= 11.5442495f);  // 8 * log2(e)
      const float mnew = keep ? mref : fmaxf(mref, cm);
      float csum = 0.f;
#pragma unroll
      for (int fj = 0; fj < 4; ++fj) {
        f16x4 fr;
#pragma unroll
        for (int r = 0; r < 4; ++r) {
          float e = exp2f(s[fi][fj][r] - mnew);   // bounded by e^8 when deferred
          fr[r] = (half_t)e; csum += e;
        }
        p[fi][fj] = fr;
      }
      csum += __shfl_xor(csum, 16);
      csum += __shfl_xor(csum, 32);
      if (keep) {
        lrun[fi] += csum;
      } else {
        const float sc = exp2f(mref - mnew);   // 0 on first chunk
        lrun[fi] = lrun[fi] * sc + csum;
        mrun[fi] = mnew;
#pragma unroll
        for (int fd = 0; fd < 4; ++fd)
#pragma unroll
          for (int r = 0; r < 4; ++r) o[fi][fd][r] *= sc;
      }
    }

    // --- PV chunk from LDS: OUT^T += vFt · P^T (K=16 per mfma) ---
#pragma unroll
    for (int kc = 0; kc < 4; ++kc) {
      const int s16 = ch * 8 + kc * 2 + (g >> 1);
      f16x4 va[4];
#pragma unroll
      for (int fd = 0; fd < 4; ++fd) {
        const int drow = fd * 16 + c;
        va[fd] = *(const f16x4*)((const char*)Vs + drow * 512 +
                                 ((s16 ^ (c & 7)) << 4) + (g & 1) * 8);
      }
#pragma unroll
      for (int fi = 0; fi < 2; ++fi)
#pragma unroll
        for (int fd = 0; fd < 4; ++fd)
          o[fi][fd] = __builtin_amdgcn_mfma_f32_16x16x16f16(va[fd], p[fi][kc], o[fi][fd], 0, 0, 0);
    }
  }

  // store head-blocked: row = qrow (128B rows), offset d = fd*16 + g*4
#pragma unroll
  for (int fi = 0; fi < 2; ++fi) {
    const float inv = 1.0f / lrun[fi];
#pragma unroll
    for (int fd = 0; fd < 4; ++fd) {
      f16x4 st;
#pragma unroll
      for (int r = 0; r < 4; ++r) st[r] = (half_t)(o[fi][fd][r] * inv);
      *(f16x4*)(ob + (long)(fi * 16 + c) * 64 + fd * 16 + g * 4) = st;
    }
  }
}

// ---------------------------------------------------------------------------
// Merged pre-pass, 64x64 tiles, (64,4) threads -> all fp16 writes are 128B.
// ---------------------------------------------------------------------------
__global__ __launch_bounds__(256, 4)
void prepass(const float* __restrict__ x, half_t* __restrict__ xhf,
             half_t* __restrict__ xT,
             const float* __restrict__ E, const float* __restrict__ F,
             half_t* __restrict__ EFt, float* __restrict__ sEF,
             const float* __restrict__ Wq, const float* __restrict__ Wk,
             const float* __restrict__ Wv, const float* __restrict__ Wo,
             half_t* __restrict__ Wqt, half_t* __restrict__ Wkt,
             half_t* __restrict__ Wvt, half_t* __restrict__ Wot)
{
  __shared__ float t[64][65];
  __shared__ float ps[4][64];
  const int tx = threadIdx.x, ty = threadIdx.y;   // (64,4)
  const int id = blockIdx.x;

  if (id < 4096) {         // ---- xpass ----
    const int bx = id & 15, by = (id >> 4) & 63, bz = id >> 10;
    const int d0 = bx * 64, l0 = by * 64;
    const float* ip = x + ((long)bz * 4096 + l0) * 1024 + d0;
    half_t* oh = xhf + ((long)bz * 4096 + l0) * 1024 + d0;
#pragma unroll
    for (int j = 0; j < 16; ++j) {
      const int row = ty + 4 * j;
      float v = ip[(long)row * 1024 + tx];
      t[row][tx] = v;
      oh[(long)row * 1024 + tx] = (half_t)v;
    }
    __syncthreads();
    half_t* ot = xT + ((long)bz * 1024 + d0) * 4096 + l0;
#pragma unroll
    for (int j = 0; j < 16; ++j) {
      const int drow = ty + 4 * j;
      ot[(long)drow * 4096 + tx] = (half_t)t[tx][drow];
    }
  } else if (id < 4608) {  // ---- efpass ----
    const int id2 = id - 4096;
    const int bx = id2 & 3, by = (id2 >> 2) & 63, zz = id2 >> 8;
    const float* in = zz ? F : E;
    half_t* oT = EFt + (long)zz * 1048576;
    float* sm = sEF + zz * 256;
    const int k0 = bx * 64, l0 = by * 64;
    float p = 0.f;
#pragma unroll
    for (int j = 0; j < 16; ++j) {
      const int row = ty + 4 * j;
      float v = in[(long)(l0 + row) * 256 + k0 + tx];
      t[row][tx] = v; p += v;
    }
    ps[ty][tx] = p;
    __syncthreads();
    if (ty == 0) {
      float a = ps[0][tx] + ps[1][tx] + ps[2][tx] + ps[3][tx];
      atomicAdd(&sm[k0 + tx], a);
    }
#pragma unroll
    for (int j = 0; j < 16; ++j) {
      const int krow = ty + 4 * j;
      oT[(long)(k0 + krow) * 4096 + l0 + tx] = (half_t)t[tx][krow];
    }
  } else {                 // ---- transposeW ----
    const int id3 = id - 4608;
    const int bx = id3 & 15, by = (id3 >> 4) & 15, zz = id3 >> 8;
    const float* in = (zz == 0) ? Wq : (zz == 1) ? Wk : (zz == 2) ? Wv : Wo;
    half_t* out = (zz == 0) ? Wqt : (zz == 1) ? Wkt : (zz == 2) ? Wvt : Wot;
    const int c0 = bx * 64, r0 = by * 64;
#pragma unroll
    for (int j = 0; j < 16; ++j) {
      const int row = ty + 4 * j;
      t[row][tx] = in[(long)(r0 + row) * 1024 + c0 + tx];
    }
    __syncthreads();
#pragma unroll
    for (int j = 0; j < 16; ++j) {
      const int crow = ty + 4 * j;
      out[(long)(c0 + crow) * 1024 + r0 + tx] = (half_t)t[tx][crow];
    }
  }
}

// sum 4 split-K f32 partial slices -> fp16
__global__ void reduce4_f16(const float* __restrict__ in, half_t* __restrict__ out) {
  long i = ((long)blockIdx.x * 256 + threadIdx.x) * 4;
  float4v a = *(const float4v*)(in + i);
#pragma unroll
  for (int ks = 1; ks < 4; ++ks) {
    float4v t = *(const float4v*)(in + (long)ks * 2097152 + i);
    a.x += t.x; a.y += t.y; a.z += t.z; a.w += t.w;
  }
  f16x4 o;
  o[0] = (half_t)a.x; o[1] = (half_t)a.y; o[2] = (half_t)a.z; o[3] = (half_t)a.w;
  *(f16x4*)(out + i) = o;
}

// ---------------------------------------------------------------------------
extern "C" void kernel_launch(void* const* d_in, const int* in_sizes, int n_in,
                              void* d_out, int out_size, void* d_ws, size_t ws_size,
                              hipStream_t stream)
{
  const float* x  = (const float*)d_in[0];
  const float* Wq = (const float*)d_in[1];
  const float* bq = (const float*)d_in[2];
  const float* Wk = (const float*)d_in[3];
  const float* bk = (const float*)d_in[4];
  const float* Wv = (const float*)d_in[5];
  const float* bv = (const float*)d_in[6];
  const float* E  = (const float*)d_in[7];
  const float* F  = (const float*)d_in[8];
  const float* Wo = (const float*)d_in[9];
  const float* bo = (const float*)d_in[10];
  float* out = (float*)d_out;

  char* ws = (char*)d_ws;
  half_t* xhf  = (half_t*)(ws);                 // 33.5MB; later reused as out_pre (head-blocked)
  half_t* xT   = (half_t*)(ws + 33554432);      // 33.5MB (dead after xEF gemm)
  half_t* qhf  = (half_t*)(ws + 67108864);      // 33.5MB, head-blocked [b][h][l][d]
  half_t* Wqt  = (half_t*)(ws + 100663296);
  half_t* Wkt  = Wqt + 1048576;
  half_t* Wvt  = Wkt + 1048576;
  half_t* Wot  = Wvt + 1048576;
  half_t* EFt  = (half_t*)(ws + 109051904);     // [512][4096]: E^T on top of F^T
  half_t* xEF  = (half_t*)(ws + 113246208);     // per b: [512][1024] = [xE; xF]
  half_t* kEb  = (half_t*)(ws + 117440512);     // per b: [16][256][64] head-blocked
  half_t* vFtb = (half_t*)(ws + 119537664);     // per b: [16][64][256]
  float*  sEF  = (float*)(ws + 121634816);      // sE[256], sF[256]
  half_t* outp = xhf;                           // out_pre (head-blocked) overlays x_f16
  float*  xEFf = (float*)d_out;                 // 33.5MB split-K partials in d_out

  hipMemsetAsync(sEF, 0, 2048, stream);
  // merged pre-pass (xpass | efpass | transposeW), 128B-write tiles
  prepass<<<dim3(5632), dim3(64, 4), 0, stream>>>(
      x, xhf, xT, E, F, EFt, sEF, Wq, Wk, Wv, Wo, Wqt, Wkt, Wvt, Wot);

  // xEF partials: [E^T; F^T] @ x_b  (M=512, N=1024, K=4096) split-K=4, plain f32
  gemm_xef<4><<<dim3(4, 8, 16), 256, 0, stream>>>(
      EFt, xT, xEFf, 4096, 4096, 4194304, 524288);
  reduce4_f16<<<2048, 256, 0, stream>>>(xEFf, xEF);

  // q = (x@Wq + bq) * hd^-0.5 * log2(e) -> head-blocked fp16 [b][16][4096][64]
  gemm_big<2,0><<<dim3(64, 4), 512, 0, stream>>>(xhf, Wqt, qhf, bq, 0.1803368801f);
  // merged kE + vF
  gemm_kevf<<<dim3(512), 256, 0, stream>>>(xEF, Wkt, Wvt, kEb, vFtb, bk, bv, sEF);
  // fused qk^T -> softmax -> PV  (writes out_pre head-blocked [b][h][l][d])
  attn_fused<<<dim3(16, 16, 4), 512, 0, stream>>>(qhf, kEb, vFtb, outp, 4096);
  // out = out_pre @ Wo + bo  (fp32; A head-blocked via AMODE=1)
  gemm_big<0,1><<<dim3(64, 4), 512, 0, stream>>>(outp, Wot, (void*)out, bo, 1.0f);
  (void)in_sizes; (void)n_in; (void)out_size; (void)ws_size;
}

// Round 24
// 207.300 us; speedup vs baseline: 1.0364x; 1.0364x over previous
//
#include <hip/hip_runtime.h>

typedef _Float16 half_t;
typedef __attribute__((ext_vector_type(8))) _Float16 f16x8;   // 8 fp16 = 4 VGPRs
typedef __attribute__((ext_vector_type(4))) _Float16 f16x4;
typedef __attribute__((ext_vector_type(4))) float f32x4;
typedef __attribute__((ext_vector_type(4))) float float4v;

__device__ __forceinline__ void gload_lds16(const void* g, void* l) {
  __builtin_amdgcn_global_load_lds(
      (const __attribute__((address_space(1))) void*)g,
      (__attribute__((address_space(3))) void*)l, 16, 0, 0);
}

// ---------------------------------------------------------------------------
// Big-GEMM (8-phase): C[16384][1024] = A * B, Bt = B^T [1024][1024].
// OUTMODE 0: f32 standard ; OUTMODE 2: f16 head-blocked [b][h][l][d]
// AMODE 0: A row-major ; AMODE 1: A head-blocked [b][h][l][64]
// NOTE: default x-major block order is deliberate — round-robin XCD dispatch
// gives each XCD an L2-resident 4MB A working set reused across n-bands
// (r23 measured: explicit swizzle broke this, FETCH 24.6->67.6MB).
// ---------------------------------------------------------------------------
template<int OUTMODE, int AMODE>
__global__ __launch_bounds__(512, 2)
void gemm_big(const half_t* __restrict__ A, const half_t* __restrict__ Bt,
              void* __restrict__ Cv, const float* __restrict__ bias, float alpha)
{
  __shared__ __attribute__((aligned(16))) char lds[131072];
  const int tid = threadIdx.x, w = tid >> 6, lane = tid & 63;
  const int wr = w >> 2, wc = w & 3;          // wave grid 2M x 4N
  const int g = lane >> 4, cc = lane & 15;
  const int m0 = blockIdx.x * 256, n0 = blockIdx.y * 256;

  const int srow2 = tid >> 2, sslot = tid & 3;
  const int swslot = sslot ^ ((srow2 >> 1) & 3);     // inverse swizzle on source
  const int swr = (g ^ ((cc >> 1) & 3)) << 4;        // swizzled read slot

  const f32x4 zero = {0.f, 0.f, 0.f, 0.f};
  f32x4 acc[8][4];
#pragma unroll
  for (int i = 0; i < 8; ++i)
#pragma unroll
    for (int j = 0; j < 4; ++j) acc[i][j] = zero;

  auto STAGE_HALF = [&](int ktile, int hh, char* sb) {
    const int kk = hh >> 1, isB = hh & 1;
    char* d = sb + isB * 32768 + kk * 16384;
    if (!isB && AMODE == 1) {
      const int r0 = m0 + srow2, r1 = r0 + 128;
      const long a0 = (((long)((r0 >> 12) * 16 + ktile) * 4096 + (r0 & 4095)) << 6)
                      + kk * 32 + swslot * 8;
      const long a1 = (((long)((r1 >> 12) * 16 + ktile) * 4096 + (r1 & 4095)) << 6)
                      + kk * 32 + swslot * 8;
      gload_lds16(A + a0, d + tid * 16);
      gload_lds16(A + a1, d + 8192 + tid * 16);
    } else {
      const half_t* src = isB ? Bt : A;
      const int base_row = isB ? n0 : m0;
      const long rowoff = (long)(base_row + srow2) * 1024 + ktile * 64 + kk * 32 + swslot * 8;
      gload_lds16(src + rowoff,          d + tid * 16);
      gload_lds16(src + rowoff + 131072, d + 8192 + tid * 16);
    }
  };

  {
    char* b0 = lds;
    STAGE_HALF(0, 0, b0); STAGE_HALF(0, 1, b0);
    STAGE_HALF(0, 2, b0); STAGE_HALF(0, 3, b0);
  }
  asm volatile("s_waitcnt vmcnt(4)" ::: "memory");
  __builtin_amdgcn_s_barrier();

#pragma unroll 1
  for (int n = 0; n < 16; ++n) {
    const char* rb = lds + ((n & 1) << 16);
    char* sb = lds + (((n + 1) & 1) << 16);
    f16x8 bf[4];
#pragma unroll
    for (int ph = 0; ph < 4; ++ph) {
      const int kk = ph >> 1, fh = ph & 1;
      f16x8 af[4];
      const char* Ah = rb + kk * 16384;
#pragma unroll
      for (int mf = 0; mf < 4; ++mf)
        af[mf] = *(const f16x8*)(Ah + (wr * 128 + fh * 64 + mf * 16 + cc) * 64 + swr);
      if (fh == 0) {
        const char* Bh = rb + 32768 + kk * 16384;
#pragma unroll
        for (int nf = 0; nf < 4; ++nf)
          bf[nf] = *(const f16x8*)(Bh + (wc * 64 + nf * 16 + cc) * 64 + swr);
      }
      if (n < 15) STAGE_HALF(n + 1, ph, sb);
      __builtin_amdgcn_sched_barrier(0);
      __builtin_amdgcn_s_barrier();
      asm volatile("s_waitcnt lgkmcnt(0)" ::: "memory");
      __builtin_amdgcn_sched_barrier(0);
      __builtin_amdgcn_s_setprio(1);
#pragma unroll
      for (int mf = 0; mf < 4; ++mf)
#pragma unroll
        for (int nf = 0; nf < 4; ++nf)
          acc[fh * 4 + mf][nf] =
              __builtin_amdgcn_mfma_f32_16x16x32_f16(af[mf], bf[nf], acc[fh * 4 + mf][nf], 0, 0, 0);
      __builtin_amdgcn_s_setprio(0);
      __builtin_amdgcn_sched_barrier(0);
      if (ph == 1) {
        if (n < 15) { asm volatile("s_waitcnt vmcnt(4)" ::: "memory"); }
        else        { asm volatile("s_waitcnt vmcnt(0)" ::: "memory"); }
      } else if (ph == 3) {
        if (n < 15) { asm volatile("s_waitcnt vmcnt(4)" ::: "memory"); }
      }
      __builtin_amdgcn_s_barrier();
    }
  }

#pragma unroll
  for (int mf = 0; mf < 8; ++mf)
#pragma unroll
    for (int nf = 0; nf < 4; ++nf)
#pragma unroll
      for (int r = 0; r < 4; ++r) {
        const int row = m0 + wr * 128 + mf * 16 + g * 4 + r;  // D: row=(l>>4)*4+reg
        const int col = n0 + wc * 64 + nf * 16 + cc;          //    col=l&15
        float v = (acc[mf][nf][r] + bias[col]) * alpha;
        if (OUTMODE == 0) {
          ((float*)Cv)[(long)row * 1024 + col] = v;
        } else {
          const int bb = row >> 12, l = row & 4095, h = col >> 6, d = col & 63;
          ((half_t*)Cv)[(((long)(bb * 16 + h) * 4096 + l) << 6) + d] = (half_t)v;
        }
      }
}

// ---------------------------------------------------------------------------
// Split-K GEMM for xEF: partials, plain f32 stores to slice ks.
// ---------------------------------------------------------------------------
template<int SK>
__global__ __launch_bounds__(256, 2)
void gemm_xef(const half_t* __restrict__ A, const half_t* __restrict__ Bt,
              float* __restrict__ Cv, int lda, int ldb, long sB, long sC)
{
  __shared__ __attribute__((aligned(16))) half_t As[128 * 32];
  __shared__ __attribute__((aligned(16))) half_t Bs[128 * 32];

  const int tid = threadIdx.x, w = tid >> 6, lane = tid & 63;
  const int wr = w >> 1, wc = w & 1;
  const int z = blockIdx.z / SK, ks = blockIdx.z % SK;
  const half_t* Ab = A;
  const half_t* Bb = Bt + (long)z * sB;
  const int m0 = blockIdx.x * 128, n0 = blockIdx.y * 128;
  const int g = lane >> 4, cc = lane & 15;
  const int srow = lane >> 2, scol = (lane & 3) * 8;

  const f32x4 zero = {0.f, 0.f, 0.f, 0.f};
  f32x4 acc[4][4];
#pragma unroll
  for (int i = 0; i < 4; ++i)
#pragma unroll
    for (int j = 0; j < 4; ++j) acc[i][j] = zero;

  const int kchunk = 4096 / SK;
  for (int kt = ks * kchunk; kt < (ks + 1) * kchunk; kt += 32) {
#pragma unroll
    for (int j = 0; j < 2; ++j) {
      const int bi = w * 2 + j;
      gload_lds16(Ab + (long)(m0 + bi * 16 + srow) * lda + kt + scol, &As[bi * 512]);
      gload_lds16(Bb + (long)(n0 + bi * 16 + srow) * ldb + kt + scol, &Bs[bi * 512]);
    }
    __syncthreads();

    f16x8 af[4], bf[4];
#pragma unroll
    for (int i = 0; i < 4; ++i)
      af[i] = *(const f16x8*)&As[(wr * 64 + i * 16 + cc) * 32 + g * 8];
#pragma unroll
    for (int j = 0; j < 4; ++j)
      bf[j] = *(const f16x8*)&Bs[(wc * 64 + j * 16 + cc) * 32 + g * 8];
#pragma unroll
    for (int i = 0; i < 4; ++i)
#pragma unroll
      for (int j = 0; j < 4; ++j)
        acc[i][j] = __builtin_amdgcn_mfma_f32_16x16x32_f16(af[i], bf[j], acc[i][j], 0, 0, 0);
    __syncthreads();
  }

  const int nb = gridDim.z / SK;
#pragma unroll
  for (int i = 0; i < 4; ++i)
#pragma unroll
    for (int j = 0; j < 4; ++j)
#pragma unroll
      for (int r = 0; r < 4; ++r) {
        const int row = m0 + wr * 64 + i * 16 + g * 4 + r;
        const int col = n0 + wc * 64 + j * 16 + cc;
        Cv[((long)ks * nb + z) * sC + (long)row * 1024 + col] = acc[i][j][r];
      }
}

// ---------------------------------------------------------------------------
// Merged kE + vF GEMM (64x64 tiles, K=1024, 512 blocks).
// ---------------------------------------------------------------------------
__global__ __launch_bounds__(256, 2)
void gemm_kevf(const half_t* __restrict__ xEF, const half_t* __restrict__ Wkt,
               const half_t* __restrict__ Wvt, half_t* __restrict__ kEb,
               half_t* __restrict__ vFtb, const float* __restrict__ bk,
               const float* __restrict__ bv, const float* __restrict__ sEF)
{
  __shared__ __attribute__((aligned(16))) half_t As[64 * 32];
  __shared__ __attribute__((aligned(16))) half_t Bs[64 * 32];
  const int tid = threadIdx.x, w = tid >> 6, lane = tid & 63;
  const int wr = w >> 1, wc = w & 1;
  const int g = lane >> 4, cc = lane & 15;
  const int srow = lane >> 2, scol = (lane & 3) * 8;

  const int bid = blockIdx.x;
  const int role = bid >> 8, lb = bid & 255;
  const half_t *Ap, *Bp;
  int m0, n0, z;
  if (role == 0) {
    m0 = (lb & 3) * 64; n0 = ((lb >> 2) & 15) * 64; z = lb >> 6;
    Ap = xEF + (long)z * 524288;  Bp = Wkt;
  } else {
    m0 = (lb & 15) * 64; n0 = ((lb >> 4) & 3) * 64; z = lb >> 6;
    Ap = Wvt;  Bp = xEF + (long)z * 524288 + 262144;
  }

  const f32x4 zero = {0.f, 0.f, 0.f, 0.f};
  f32x4 acc[2][2];
#pragma unroll
  for (int i = 0; i < 2; ++i)
#pragma unroll
    for (int j = 0; j < 2; ++j) acc[i][j] = zero;

  for (int kt = 0; kt < 1024; kt += 32) {
    gload_lds16(Ap + (long)(m0 + w * 16 + srow) * 1024 + kt + scol, &As[w * 512]);
    gload_lds16(Bp + (long)(n0 + w * 16 + srow) * 1024 + kt + scol, &Bs[w * 512]);
    __syncthreads();
    f16x8 af[2], bf[2];
#pragma unroll
    for (int i = 0; i < 2; ++i)
      af[i] = *(const f16x8*)&As[(wr * 32 + i * 16 + cc) * 32 + g * 8];
#pragma unroll
    for (int j = 0; j < 2; ++j)
      bf[j] = *(const f16x8*)&Bs[(wc * 32 + j * 16 + cc) * 32 + g * 8];
#pragma unroll
    for (int i = 0; i < 2; ++i)
#pragma unroll
      for (int j = 0; j < 2; ++j)
        acc[i][j] = __builtin_amdgcn_mfma_f32_16x16x32_f16(af[i], bf[j], acc[i][j], 0, 0, 0);
    __syncthreads();
  }

#pragma unroll
  for (int i = 0; i < 2; ++i)
#pragma unroll
    for (int j = 0; j < 2; ++j)
#pragma unroll
      for (int r = 0; r < 4; ++r) {
        const int row = m0 + wr * 32 + i * 16 + g * 4 + r;
        const int col = n0 + wc * 32 + j * 16 + cc;
        float v = acc[i][j][r];
        if (role == 0) {
          v += sEF[row] * bk[col];
          kEb[(long)z * 262144 + (long)(col >> 6) * 16384 + (long)row * 64 + (col & 63)]
              = (half_t)v;
        } else {
          v += bv[row] * sEF[256 + col];
          vFtb[(long)z * 262144 + (long)row * 256 + col] = (half_t)v;
        }
      }
}

// ---------------------------------------------------------------------------
// Fused attention v9b (single-tile): stage kE+vF per block, one 256-row
// q-tile per block (grid 16x16x4). exp2 softmax (logits pre-scaled by log2e),
// T13 defer-max. Output head-blocked [b][h][l][d].
// ---------------------------------------------------------------------------
__global__ __launch_bounds__(512, 2)
void attn_fused(const half_t* __restrict__ qhb, const half_t* __restrict__ kEh,
                const half_t* __restrict__ vFt, half_t* __restrict__ outp, int L)
{
  __shared__ __attribute__((aligned(16))) half_t Ks[256 * 64];  // 32KB
  __shared__ __attribute__((aligned(16))) half_t Vs[64 * 256];  // 32KB
  const int tid = threadIdx.x, w = tid >> 6, lane = tid & 63;
  const int g = lane >> 4, c = lane & 15;
  const int l0 = blockIdx.x * 256, h = blockIdx.y, b = blockIdx.z;

  const half_t* keh = kEh + (long)(b * 16 + h) * 16384;          // [256][64]
  const half_t* vfh = vFt + (long)b * 262144 + (long)h * 16384;  // [64][256]

  // ---- stage kE -> Ks and vF -> Vs (swizzled source, linear dest) ----
#pragma unroll
  for (int i = 0; i < 4; ++i) {
    const int row = i * 64 + (tid >> 3), slot = tid & 7;
    gload_lds16(keh + row * 64 + ((slot ^ (row & 7)) << 3),
                (char*)Ks + i * 8192 + tid * 16);
  }
#pragma unroll
  for (int i = 0; i < 4; ++i) {
    const int row = i * 16 + (tid >> 5), slot = tid & 31;
    gload_lds16(vfh + row * 256 + ((slot ^ (row & 7)) << 3),
                (char*)Vs + i * 8192 + tid * 16);
  }

  const long lbase = (long)(b * 16 + h) * 4096 + l0;
  const half_t* qpan = qhb + lbase * 64;          // [256][64]
  half_t* ob = outp + (lbase + w * 32) * 64;      // head-blocked out

  // q direct to registers (overlaps the staging loads)
  f16x8 qf[2][2];
#pragma unroll
  for (int fi = 0; fi < 2; ++fi)
#pragma unroll
    for (int ks = 0; ks < 2; ++ks)
      qf[fi][ks] = *(const f16x8*)(qpan + (w * 32 + fi * 16 + c) * 64 + ks * 32 + g * 8);

  __syncthreads();   // staged kE/vF visible

  const f32x4 zero = {0.f, 0.f, 0.f, 0.f};
  f32x4 o[2][4];
#pragma unroll
  for (int fi = 0; fi < 2; ++fi)
#pragma unroll
    for (int fd = 0; fd < 4; ++fd) o[fi][fd] = zero;
  float mrun[2] = {-3.0e38f, -3.0e38f};
  float lrun[2] = {0.f, 0.f};

  for (int ch = 0; ch < 4; ++ch) {
    // --- QK^T chunk from LDS: S^T = kE · q^T ---
    f32x4 s[2][4];
#pragma unroll
    for (int fi = 0; fi < 2; ++fi)
#pragma unroll
      for (int fj = 0; fj < 4; ++fj) s[fi][fj] = zero;
#pragma unroll
    for (int fj = 0; fj < 4; ++fj) {
      const int krow = ch * 64 + fj * 16 + c;
      const char* kb = (const char*)Ks + krow * 128;
      f16x8 k0 = *(const f16x8*)(kb + ((g ^ (c & 7)) << 4));
      f16x8 k1 = *(const f16x8*)(kb + (((4 + g) ^ (c & 7)) << 4));
#pragma unroll
      for (int fi = 0; fi < 2; ++fi) {
        s[fi][fj] = __builtin_amdgcn_mfma_f32_16x16x32_f16(k0, qf[fi][0], s[fi][fj], 0, 0, 0);
        s[fi][fj] = __builtin_amdgcn_mfma_f32_16x16x32_f16(k1, qf[fi][1], s[fi][fj], 0, 0, 0);
      }
    }

    // --- online softmax (log2-domain, native exp2) with defer-max ---
    f16x4 p[2][4];
#pragma unroll
    for (int fi = 0; fi < 2; ++fi) {
      float cm = -3.0e38f;
#pragma unroll
      for (int fj = 0; fj < 4; ++fj)
#pragma unroll
        for (int r = 0; r < 4; ++r) cm = fmaxf(cm, s[fi][fj][r]);
      cm = fmaxf(cm, __shfl_xor(cm, 16));
      cm = fmaxf(cm, __shfl_xor(cm, 32));
      const float mref = mrun[fi];
      const bool keep = __all(cm - mref <= 11.5442495f);  // 8 * log2(e)
      const float mnew = keep ? mref : fmaxf(mref, cm);
      float csum = 0.f;
#pragma unroll
      for (int fj = 0; fj < 4; ++fj) {
        f16x4 fr;
#pragma unroll
        for (int r = 0; r < 4; ++r) {
          float e = exp2f(s[fi][fj][r] - mnew);   // bounded by e^8 when deferred
          fr[r] = (half_t)e; csum += e;
        }
        p[fi][fj] = fr;
      }
      csum += __shfl_xor(csum, 16);
      csum += __shfl_xor(csum, 32);
      if (keep) {
        lrun[fi] += csum;
      } else {
        const float sc = exp2f(mref - mnew);   // 0 on first chunk
        lrun[fi] = lrun[fi] * sc + csum;
        mrun[fi] = mnew;
#pragma unroll
        for (int fd = 0; fd < 4; ++fd)
#pragma unroll
          for (int r = 0; r < 4; ++r) o[fi][fd][r] *= sc;
      }
    }

    // --- PV chunk from LDS: OUT^T += vFt · P^T (K=16 per mfma) ---
#pragma unroll
    for (int kc = 0; kc < 4; ++kc) {
      const int s16 = ch * 8 + kc * 2 + (g >> 1);
      f16x4 va[4];
#pragma unroll
      for (int fd = 0; fd < 4; ++fd) {
        const int drow = fd * 16 + c;
        va[fd] = *(const f16x4*)((const char*)Vs + drow * 512 +
                                 ((s16 ^ (c & 7)) << 4) + (g & 1) * 8);
      }
#pragma unroll
      for (int fi = 0; fi < 2; ++fi)
#pragma unroll
        for (int fd = 0; fd < 4; ++fd)
          o[fi][fd] = __builtin_amdgcn_mfma_f32_16x16x16f16(va[fd], p[fi][kc], o[fi][fd], 0, 0, 0);
    }
  }

  // store head-blocked: row = qrow (128B rows), offset d = fd*16 + g*4
#pragma unroll
  for (int fi = 0; fi < 2; ++fi) {
    const float inv = 1.0f / lrun[fi];
#pragma unroll
    for (int fd = 0; fd < 4; ++fd) {
      f16x4 st;
#pragma unroll
      for (int r = 0; r < 4; ++r) st[r] = (half_t)(o[fi][fd][r] * inv);
      *(f16x4*)(ob + (long)(fi * 16 + c) * 64 + fd * 16 + g * 4) = st;
    }
  }
}

// ---------------------------------------------------------------------------
// Merged pre-pass, 64x64 tiles, (64,4) threads -> all fp16 writes are 128B.
// ---------------------------------------------------------------------------
__global__ __launch_bounds__(256, 4)
void prepass(const float* __restrict__ x, half_t* __restrict__ xhf,
             half_t* __restrict__ xT,
             const float* __restrict__ E, const float* __restrict__ F,
             half_t* __restrict__ EFt, float* __restrict__ sEF,
             const float* __restrict__ Wq, const float* __restrict__ Wk,
             const float* __restrict__ Wv, const float* __restrict__ Wo,
             half_t* __restrict__ Wqt, half_t* __restrict__ Wkt,
             half_t* __restrict__ Wvt, half_t* __restrict__ Wot)
{
  __shared__ float t[64][65];
  __shared__ float ps[4][64];
  const int tx = threadIdx.x, ty = threadIdx.y;   // (64,4)
  const int id = blockIdx.x;

  if (id < 4096) {         // ---- xpass ----
    const int bx = id & 15, by = (id >> 4) & 63, bz = id >> 10;
    const int d0 = bx * 64, l0 = by * 64;
    const float* ip = x + ((long)bz * 4096 + l0) * 1024 + d0;
    half_t* oh = xhf + ((long)bz * 4096 + l0) * 1024 + d0;
#pragma unroll
    for (int j = 0; j < 16; ++j) {
      const int row = ty + 4 * j;
      float v = ip[(long)row * 1024 + tx];
      t[row][tx] = v;
      oh[(long)row * 1024 + tx] = (half_t)v;
    }
    __syncthreads();
    half_t* ot = xT + ((long)bz * 1024 + d0) * 4096 + l0;
#pragma unroll
    for (int j = 0; j < 16; ++j) {
      const int drow = ty + 4 * j;
      ot[(long)drow * 4096 + tx] = (half_t)t[tx][drow];
    }
  } else if (id < 4608) {  // ---- efpass ----
    const int id2 = id - 4096;
    const int bx = id2 & 3, by = (id2 >> 2) & 63, zz = id2 >> 8;
    const float* in = zz ? F : E;
    half_t* oT = EFt + (long)zz * 1048576;
    float* sm = sEF + zz * 256;
    const int k0 = bx * 64, l0 = by * 64;
    float p = 0.f;
#pragma unroll
    for (int j = 0; j < 16; ++j) {
      const int row = ty + 4 * j;
      float v = in[(long)(l0 + row) * 256 + k0 + tx];
      t[row][tx] = v; p += v;
    }
    ps[ty][tx] = p;
    __syncthreads();
    if (ty == 0) {
      float a = ps[0][tx] + ps[1][tx] + ps[2][tx] + ps[3][tx];
      atomicAdd(&sm[k0 + tx], a);
    }
#pragma unroll
    for (int j = 0; j < 16; ++j) {
      const int krow = ty + 4 * j;
      oT[(long)(k0 + krow) * 4096 + l0 + tx] = (half_t)t[tx][krow];
    }
  } else {                 // ---- transposeW ----
    const int id3 = id - 4608;
    const int bx = id3 & 15, by = (id3 >> 4) & 15, zz = id3 >> 8;
    const float* in = (zz == 0) ? Wq : (zz == 1) ? Wk : (zz == 2) ? Wv : Wo;
    half_t* out = (zz == 0) ? Wqt : (zz == 1) ? Wkt : (zz == 2) ? Wvt : Wot;
    const int c0 = bx * 64, r0 = by * 64;
#pragma unroll
    for (int j = 0; j < 16; ++j) {
      const int row = ty + 4 * j;
      t[row][tx] = in[(long)(r0 + row) * 1024 + c0 + tx];
    }
    __syncthreads();
#pragma unroll
    for (int j = 0; j < 16; ++j) {
      const int crow = ty + 4 * j;
      out[(long)(c0 + crow) * 1024 + r0 + tx] = (half_t)t[tx][crow];
    }
  }
}

// sum 4 split-K f32 partial slices -> fp16
__global__ void reduce4_f16(const float* __restrict__ in, half_t* __restrict__ out) {
  long i = ((long)blockIdx.x * 256 + threadIdx.x) * 4;
  float4v a = *(const float4v*)(in + i);
#pragma unroll
  for (int ks = 1; ks < 4; ++ks) {
    float4v t = *(const float4v*)(in + (long)ks * 2097152 + i);
    a.x += t.x; a.y += t.y; a.z += t.z; a.w += t.w;
  }
  f16x4 o;
  o[0] = (half_t)a.x; o[1] = (half_t)a.y; o[2] = (half_t)a.z; o[3] = (half_t)a.w;
  *(f16x4*)(out + i) = o;
}

// ---------------------------------------------------------------------------
extern "C" void kernel_launch(void* const* d_in, const int* in_sizes, int n_in,
                              void* d_out, int out_size, void* d_ws, size_t ws_size,
                              hipStream_t stream)
{
  const float* x  = (const float*)d_in[0];
  const float* Wq = (const float*)d_in[1];
  const float* bq = (const float*)d_in[2];
  const float* Wk = (const float*)d_in[3];
  const float* bk = (const float*)d_in[4];
  const float* Wv = (const float*)d_in[5];
  const float* bv = (const float*)d_in[6];
  const float* E  = (const float*)d_in[7];
  const float* F  = (const float*)d_in[8];
  const float* Wo = (const float*)d_in[9];
  const float* bo = (const float*)d_in[10];
  float* out = (float*)d_out;

  char* ws = (char*)d_ws;
  half_t* xhf  = (half_t*)(ws);                 // 33.5MB; later reused as out_pre (head-blocked)
  half_t* xT   = (half_t*)(ws + 33554432);      // 33.5MB (dead after xEF gemm)
  half_t* qhf  = (half_t*)(ws + 67108864);      // 33.5MB, head-blocked [b][h][l][d]
  half_t* Wqt  = (half_t*)(ws + 100663296);
  half_t* Wkt  = Wqt + 1048576;
  half_t* Wvt  = Wkt + 1048576;
  half_t* Wot  = Wvt + 1048576;
  half_t* EFt  = (half_t*)(ws + 109051904);     // [512][4096]: E^T on top of F^T
  half_t* xEF  = (half_t*)(ws + 113246208);     // per b: [512][1024] = [xE; xF]
  half_t* kEb  = (half_t*)(ws + 117440512);     // per b: [16][256][64] head-blocked
  half_t* vFtb = (half_t*)(ws + 119537664);     // per b: [16][64][256]
  float*  sEF  = (float*)(ws + 121634816);      // sE[256], sF[256]
  half_t* outp = xhf;                           // out_pre (head-blocked) overlays x_f16
  float*  xEFf = (float*)d_out;                 // 33.5MB split-K partials in d_out

  hipMemsetAsync(sEF, 0, 2048, stream);
  // merged pre-pass (xpass | efpass | transposeW), 128B-write tiles
  prepass<<<dim3(5632), dim3(64, 4), 0, stream>>>(
      x, xhf, xT, E, F, EFt, sEF, Wq, Wk, Wv, Wo, Wqt, Wkt, Wvt, Wot);

  // xEF partials: [E^T; F^T] @ x_b  (M=512, N=1024, K=4096) split-K=4, plain f32
  gemm_xef<4><<<dim3(4, 8, 16), 256, 0, stream>>>(
      EFt, xT, xEFf, 4096, 4096, 4194304, 524288);
  reduce4_f16<<<2048, 256, 0, stream>>>(xEFf, xEF);

  // q = (x@Wq + bq) * hd^-0.5 * log2(e) -> head-blocked fp16 [b][16][4096][64]
  gemm_big<2,0><<<dim3(64, 4), 512, 0, stream>>>(xhf, Wqt, qhf, bq, 0.1803368801f);
  // merged kE + vF
  gemm_kevf<<<dim3(512), 256, 0, stream>>>(xEF, Wkt, Wvt, kEb, vFtb, bk, bv, sEF);
  // fused qk^T -> softmax -> PV  (writes out_pre head-blocked [b][h][l][d])
  attn_fused<<<dim3(16, 16, 4), 512, 0, stream>>>(qhf, kEb, vFtb, outp, 4096);
  // out = out_pre @ Wo + bo  (fp32; A head-blocked via AMODE=1)
  gemm_big<0,1><<<dim3(64, 4), 512, 0, stream>>>(outp, Wot, (void*)out, bo, 1.0f);
  (void)in_sizes; (void)n_in; (void)out_size; (void)ws_size;
}